// Round 3
// baseline (320.522 us; speedup 1.0000x reference)
//
#include <hip/hip_runtime.h>

#define T_SIZE 4194304
#define B_SIZE 131072
#define KD 8

// Kernel 1: per-slot init. Each thread handles 4 consecutive slots.
// new_longevity is written as FLOAT (harness reads entire d_out as float32).
__global__ void vault_init_kernel(const float* __restrict__ trust_scores,
                                  const int* __restrict__ longevity,
                                  float* __restrict__ new_scores,
                                  float* __restrict__ new_longevity,
                                  int* __restrict__ min_row) {
    int t = blockIdx.x * blockDim.x + threadIdx.x;  // [0, T_SIZE/4)
    if (t < T_SIZE / 4) {
        float4 s = ((const float4*)trust_scores)[t];
        int4 l = ((const int4*)longevity)[t];
        float4 lf = make_float4((float)l.x, (float)l.y, (float)l.z, (float)l.w);
        ((float4*)new_scores)[t] = s;
        ((float4*)new_longevity)[t] = lf;
        ((int4*)min_row)[t] = make_int4(B_SIZE, B_SIZE, B_SIZE, B_SIZE);
    }
}

// Kernel 2: per-row scatter. Scores are all >= 0 (uniform [0,1)), so int-punned
// atomicMax on the float bits is order-preserving. Longevity counts are small
// integers -> exact in fp32 atomicAdd.
__global__ void vault_scatter_kernel(const float* __restrict__ survivorship,
                                     const int* __restrict__ indices,
                                     float* __restrict__ new_scores,
                                     float* __restrict__ new_longevity) {
    int i = blockIdx.x * blockDim.x + threadIdx.x;
    if (i < B_SIZE) {
        int idx = indices[i];
        atomicMax((int*)(new_scores + idx), __float_as_int(survivorship[i]));
        atomicAdd(new_longevity + idx, 1.0f);
    }
}

// Kernel 3: per-row winner selection + query gather (after kernel 2 completes).
__global__ void vault_winner_kernel(const float* __restrict__ survivorship,
                                    const int* __restrict__ indices,
                                    const float* __restrict__ trust_scores,
                                    const float* __restrict__ new_scores,
                                    float* __restrict__ query_scores,
                                    int* __restrict__ min_row) {
    int i = blockIdx.x * blockDim.x + threadIdx.x;
    if (i < B_SIZE) {
        int idx = indices[i];
        float s = survivorship[i];
        float oldv = trust_scores[idx];
        float finalv = new_scores[idx];
        query_scores[i] = finalv;
        // win = strictly beats old score AND equals the final (max) score.
        if (s > oldv && s >= finalv) {
            atomicMin(min_row + idx, i);
        }
    }
}

// Kernel 4: per-slot table write, 32 B per thread (2x float4).
__global__ void vault_table_kernel(const float* __restrict__ residues,
                                   const float* __restrict__ trust_table,
                                   const int* __restrict__ min_row,
                                   float* __restrict__ new_table) {
    int t = blockIdx.x * blockDim.x + threadIdx.x;
    if (t < T_SIZE) {
        int r = min_row[t];
        const float4* src = (r < B_SIZE)
            ? (const float4*)(residues + (size_t)r * KD)
            : (const float4*)(trust_table + (size_t)t * KD);
        float4 a = src[0];
        float4 b = src[1];
        float4* dst = (float4*)(new_table + (size_t)t * KD);
        dst[0] = a;
        dst[1] = b;
    }
}

extern "C" void kernel_launch(void* const* d_in, const int* in_sizes, int n_in,
                              void* d_out, int out_size, void* d_ws, size_t ws_size,
                              hipStream_t stream) {
    const float* residues      = (const float*)d_in[0];   // [B, 8]
    const float* survivorship  = (const float*)d_in[1];   // [B]
    const float* trust_table   = (const float*)d_in[2];   // [T, 8]
    const float* trust_scores  = (const float*)d_in[3];   // [T]
    const int*   longevity     = (const int*)d_in[4];     // [T]
    const int*   indices       = (const int*)d_in[5];     // [B]

    // Output layout (concatenated flat, return order, ALL float32):
    // query_scores [B] | new_table [T*8] | new_scores [T] | new_longevity [T]
    float* query_scores  = (float*)d_out;
    float* new_table     = query_scores + B_SIZE;
    float* new_scores    = new_table + (size_t)T_SIZE * KD;
    float* new_longevity = new_scores + T_SIZE;

    int* min_row = (int*)d_ws;  // [T] scratch

    const int blk = 256;

    // 1) init new_scores / new_longevity / min_row (4 slots per thread)
    vault_init_kernel<<<(T_SIZE / 4 + blk - 1) / blk, blk, 0, stream>>>(
        trust_scores, longevity, new_scores, new_longevity, min_row);

    // 2) scatter-max + longevity add
    vault_scatter_kernel<<<(B_SIZE + blk - 1) / blk, blk, 0, stream>>>(
        survivorship, indices, new_scores, new_longevity);

    // 3) winner rows + query gather
    vault_winner_kernel<<<(B_SIZE + blk - 1) / blk, blk, 0, stream>>>(
        survivorship, indices, trust_scores, new_scores, query_scores, min_row);

    // 4) table rewrite
    vault_table_kernel<<<(T_SIZE + blk - 1) / blk, blk, 0, stream>>>(
        residues, trust_table, min_row, new_table);
}

// Round 4
// 315.341 us; speedup vs baseline: 1.0164x; 1.0164x over previous
//
#include <hip/hip_runtime.h>

#define T_SIZE 4194304
#define B_SIZE 131072
#define KD 8
#define ROW_BLOCKS (B_SIZE / 256)      // 512 blocks handle the query gather
#define SLOT_BLOCKS (T_SIZE / 256)     // 16384 blocks handle slots

typedef unsigned long long u64;
typedef unsigned int u32;

// Kernel 1: init. packed[T] = 0 (u64 argmax accumulator), new_longevity = (float)longevity.
// Each thread: 4 slots. packed=0 is a safe identity: every real row packs to
// (surv_bits<<32)|~row > 0 (row < 2^17 -> ~row >= 0xFFFE0000).
__global__ void vault_init_kernel(const int* __restrict__ longevity,
                                  float* __restrict__ new_longevity,
                                  u64* __restrict__ packed) {
    int t = blockIdx.x * blockDim.x + threadIdx.x;  // [0, T_SIZE/4)
    ulonglong2 z = {0ull, 0ull};
    ((ulonglong2*)packed)[2 * t]     = z;
    ((ulonglong2*)packed)[2 * t + 1] = z;
    int4 l = ((const int4*)longevity)[t];
    ((float4*)new_longevity)[t] =
        make_float4((float)l.x, (float)l.y, (float)l.z, (float)l.w);
}

// Kernel 2: single scatter pass. Packed u64 atomicMax computes, per slot, the
// max survivorship AND the minimum row index among ties (first-winner rule).
// fp32 atomicAdd counts longevity (small ints, exact).
__global__ void vault_scatter_kernel(const float* __restrict__ survivorship,
                                     const int* __restrict__ indices,
                                     u64* __restrict__ packed,
                                     float* __restrict__ new_longevity) {
    int i = blockIdx.x * blockDim.x + threadIdx.x;
    int idx = indices[i];
    u32 bits = __float_as_uint(survivorship[i]);   // surv >= 0 -> bit order == numeric order
    u64 p = ((u64)bits << 32) | (u64)(~(u32)i);    // bigger surv wins; ties -> smaller row wins
    atomicMax(packed + idx, p);
    atomicAdd(new_longevity + idx, 1.0f);
}

// Kernel 3: fused finalize. Blocks [0, ROW_BLOCKS) do the row-indexed query
// gather (latency-bound, hides under the slot stream); blocks [ROW_BLOCKS, ...)
// do the slot-indexed new_scores + table rewrite (BW-bound).
__global__ void vault_finalize_kernel(const float* __restrict__ residues,
                                      const float* __restrict__ trust_table,
                                      const float* __restrict__ trust_scores,
                                      const int* __restrict__ indices,
                                      const u64* __restrict__ packed,
                                      float* __restrict__ query_scores,
                                      float* __restrict__ new_table,
                                      float* __restrict__ new_scores) {
    int b = blockIdx.x;
    if (b < ROW_BLOCKS) {
        int i = b * 256 + threadIdx.x;
        int idx = indices[i];
        u64 p = packed[idx];                        // own row touched this slot -> p > 0
        float ms = __uint_as_float((u32)(p >> 32));
        float oldv = trust_scores[idx];
        query_scores[i] = fmaxf(oldv, ms);
    } else {
        int t = (b - ROW_BLOCKS) * 256 + threadIdx.x;
        u64 p = packed[t];
        float ms = __uint_as_float((u32)(p >> 32)); // untouched slot: p=0 -> ms=0.0
        float oldv = trust_scores[t];
        new_scores[t] = fmaxf(oldv, ms);
        // Winner iff max survivorship strictly beats the old score.
        int r = (int)(~(u32)p);                     // min row among argmax ties
        const float4* src = (ms > oldv)
            ? (const float4*)(residues + (size_t)r * KD)
            : (const float4*)(trust_table + (size_t)t * KD);
        float4 a = src[0];
        float4 c = src[1];
        float4* dst = (float4*)(new_table + (size_t)t * KD);
        dst[0] = a;
        dst[1] = c;
    }
}

extern "C" void kernel_launch(void* const* d_in, const int* in_sizes, int n_in,
                              void* d_out, int out_size, void* d_ws, size_t ws_size,
                              hipStream_t stream) {
    const float* residues      = (const float*)d_in[0];   // [B, 8]
    const float* survivorship  = (const float*)d_in[1];   // [B]
    const float* trust_table   = (const float*)d_in[2];   // [T, 8]
    const float* trust_scores  = (const float*)d_in[3];   // [T]
    const int*   longevity     = (const int*)d_in[4];     // [T]
    const int*   indices       = (const int*)d_in[5];     // [B]

    // Output layout (concatenated flat, return order, ALL read back as float32):
    // query_scores [B] | new_table [T*8] | new_scores [T] | new_longevity [T]
    float* query_scores  = (float*)d_out;
    float* new_table     = query_scores + B_SIZE;
    float* new_scores    = new_table + (size_t)T_SIZE * KD;
    float* new_longevity = new_scores + T_SIZE;

    u64* packed = (u64*)d_ws;  // [T] scratch (32 MB)

    const int blk = 256;

    // 1) init packed + longevity->float  (1M threads, 4 slots each)
    vault_init_kernel<<<T_SIZE / 4 / blk, blk, 0, stream>>>(
        longevity, new_longevity, packed);

    // 2) single atomic scatter pass (argmax + count)
    vault_scatter_kernel<<<B_SIZE / blk, blk, 0, stream>>>(
        survivorship, indices, packed, new_longevity);

    // 3) fused query gather + slot finalize (rows first so their latency
    //    overlaps the long BW-bound slot tail)
    vault_finalize_kernel<<<ROW_BLOCKS + SLOT_BLOCKS, blk, 0, stream>>>(
        residues, trust_table, trust_scores, indices, packed,
        query_scores, new_table, new_scores);
}